// Round 2
// baseline (388.983 us; speedup 1.0000x reference)
//
#include <hip/hip_runtime.h>

// Xonv2D: location-dependent 3x3 conv.
//   x:       (B=4, CIN=16, H=128, W=128)  fp32
//   weights: (H, W, COUT=16, CIN=16, 3, 3) fp32   -- 151 MB, the traffic driver
//   bias:    (H, W, COUT) fp32
//   out:     (B, COUT, H, W) fp32
//
// V2: weight stream now goes global -> LDS via __builtin_amdgcn_global_load_lds
// (16B per lane, fully coalesced: each instruction covers one contiguous 1KB
// segment), instead of v1's 144B-strided per-lane float4 gather (~64 cache-line
// segments per instruction). One wave per site; 9KB LDS buffer per wave
// (36KB/block -> 4 blocks/CU). After one __syncthreads (drains vmcnt), each
// lane reads its 36 weights from LDS (ds_read_b128 x9) and runs the same
// register-resident batch-4 accumulation as v1.

#define HWD  128
#define CIND 16
#define COUTD 16
#define BATCH 4

typedef __attribute__((address_space(3))) void       lds_void_t;
typedef const __attribute__((address_space(1))) void glb_void_t;

__global__ __launch_bounds__(256, 4) void xonv2d_kernel(
    const float* __restrict__ x,
    const float* __restrict__ wts,
    const float* __restrict__ bias,
    float* __restrict__ out)
{
    __shared__ float4 wsm[4 * 576];   // 4 waves x 576 float4 (9216 B) = 36 KB

    const int lane = threadIdx.x & 63;
    const int wave = threadIdx.x >> 6;
    const int site = blockIdx.x * 4 + wave;   // 0 .. 16383
    const int h = site >> 7;
    const int w = site & 127;

    const int o = lane & 15;    // output channel
    const int g = lane >> 4;    // channel group: c in [4g, 4g+4)
    const int c0 = g * 4;

    // ---- async coalesced staging: site's 576 float4s -> LDS ----
    // chunk j: lane l fetches global float4 (site*576 + j*64 + l); the wave's
    // 64 lanes cover one contiguous 1KB segment. LDS dst base is wave-uniform;
    // HW writes base + lane*16.
    {
        const float4* gbase = (const float4*)wts + (size_t)site * 576 + lane;
        #pragma unroll
        for (int j = 0; j < 9; ++j) {
            __builtin_amdgcn_global_load_lds(
                (glb_void_t*)(gbase + j * 64),
                (lds_void_t*)(&wsm[wave * 576 + j * 64]),
                16, 0, 0);
        }
    }

    // bias prefetch (tiny, overlaps the weight DMA)
    float bv = 0.f;
    if (g == 0) bv = bias[(size_t)site * COUTD + o];

    __syncthreads();   // drains vmcnt -> LDS weights valid

    // ---- pull this lane's 36 weights (9 float4s) from LDS ----
    float4 wv[9];
    {
        const float4* lp = &wsm[wave * 576 + o * 36 + g * 9];
        #pragma unroll
        for (int j = 0; j < 9; ++j) wv[j] = lp[j];
    }
    const float* wf = (const float*)wv;

    float acc[BATCH] = {0.f, 0.f, 0.f, 0.f};

    const bool interior = (h >= 1) & (h <= HWD - 2) & (w >= 1) & (w <= HWD - 2);

    if (interior) {
        #pragma unroll
        for (int cc = 0; cc < 4; ++cc) {
            const float* xc = x + ((size_t)(c0 + cc) * HWD + (h - 1)) * HWD + (w - 1);
            #pragma unroll
            for (int b = 0; b < BATCH; ++b) {
                const float* xb = xc + (size_t)b * (CIND * HWD * HWD);
                #pragma unroll
                for (int kh = 0; kh < 3; ++kh) {
                    #pragma unroll
                    for (int kw = 0; kw < 3; ++kw) {
                        acc[b] = fmaf(xb[kh * HWD + kw], wf[cc * 9 + kh * 3 + kw], acc[b]);
                    }
                }
            }
        }
    } else {
        #pragma unroll
        for (int cc = 0; cc < 4; ++cc) {
            #pragma unroll
            for (int b = 0; b < BATCH; ++b) {
                const float* xb = x + ((size_t)b * CIND + (c0 + cc)) * (HWD * HWD);
                #pragma unroll
                for (int kh = 0; kh < 3; ++kh) {
                    const int hy = h + kh - 1;
                    #pragma unroll
                    for (int kw = 0; kw < 3; ++kw) {
                        const int wx = w + kw - 1;
                        const bool ok = (hy >= 0) & (hy < HWD) & (wx >= 0) & (wx < HWD);
                        const float xv = ok ? xb[hy * HWD + wx] : 0.f;
                        acc[b] = fmaf(xv, wf[cc * 9 + kh * 3 + kw], acc[b]);
                    }
                }
            }
        }
    }

    // ---- reduce the 4 c-groups (lanes o, o+16, o+32, o+48) ----
    #pragma unroll
    for (int b = 0; b < BATCH; ++b) {
        float v = acc[b];
        v += __shfl_down(v, 32);
        v += __shfl_down(v, 16);
        acc[b] = v;
    }

    if (g == 0) {
        #pragma unroll
        for (int b = 0; b < BATCH; ++b) {
            out[((size_t)b * COUTD + o) * (HWD * HWD) + h * HWD + w] = acc[b] + bv;
        }
    }
}

extern "C" void kernel_launch(void* const* d_in, const int* in_sizes, int n_in,
                              void* d_out, int out_size, void* d_ws, size_t ws_size,
                              hipStream_t stream) {
    const float* x    = (const float*)d_in[0];
    const float* wts  = (const float*)d_in[1];
    const float* bias = (const float*)d_in[2];
    float* out = (float*)d_out;

    // 16384 sites, 4 waves (= 4 sites) per 256-thread block.
    const int blocks = (HWD * HWD) / 4;
    xonv2d_kernel<<<blocks, 256, 0, stream>>>(x, wts, bias, out);
}

// Round 4
// 272.268 us; speedup vs baseline: 1.4287x; 1.4287x over previous
//
#include <hip/hip_runtime.h>

// Xonv2D: location-dependent 3x3 conv.
//   x:       (B=4, CIN=16, H=128, W=128)  fp32
//   weights: (H, W, COUT=16, CIN=16, 3, 3) fp32   -- 151 MB, the traffic driver
//   bias:    (H, W, COUT) fp32
//   out:     (B, COUT, H, W) fp32
//
// V4 = V3 with the OOB fix: interior fast path requires w <= 125 so the
// float4 row loads (columns w-1..w+2) never index past column 127. At w==126
// the 4th (unused) element of the row-(h+1) load could land exactly 1 float
// past the end of x (site 126,126 / b=3 / c=15) -> page fault. w==126 now
// takes the predicated border path (wave-uniform, ~4% of sites).
//
// Structure: one wave/site, lane = g*16+o; weights per-lane contiguous 144B
// as 9 nontemporal float4 loads; x window rows as dword-aligned float4
// (48 load instrs/wave); batch-4 register accumulation; XCD banding
// (blockIdx%8 -> band of 2048 consecutive sites); butterfly reduce
// (shfl_xor 32,16) + single 64-lane store. No LDS, no barriers.

#define HWD  128
#define CIND 16
#define COUTD 16
#define BATCH 4

typedef float f4  __attribute__((ext_vector_type(4)));
typedef float f4u __attribute__((ext_vector_type(4), aligned(4)));

__global__ __launch_bounds__(256) void xonv2d_kernel(
    const float* __restrict__ x,
    const float* __restrict__ wts,
    const float* __restrict__ bias,
    float* __restrict__ out)
{
    const int lane = threadIdx.x & 63;
    const int wave = threadIdx.x >> 6;

    // XCD banding: XCD k = blockIdx%8 handles sites [k*2048, (k+1)*2048).
    const int xcd = blockIdx.x & 7;
    const int idx = blockIdx.x >> 3;
    const int site = xcd * 2048 + idx * 4 + wave;   // 0 .. 16383
    const int h = site >> 7;
    const int w = site & 127;

    const int o = lane & 15;    // output channel
    const int g = lane >> 4;    // channel group: c in [4g, 4g+4)
    const int c0 = g * 4;

    // ---- weight stream: 36 contiguous floats (9 aligned float4s), nontemporal ----
    const f4* wp = (const f4*)(wts + (size_t)site * (COUTD * CIND * 9)
                                    + o * (CIND * 9) + g * 36);
    f4 wv[9];
    #pragma unroll
    for (int i = 0; i < 9; ++i) wv[i] = __builtin_nontemporal_load(wp + i);
    const float* wf = (const float*)wv;

    // bias: one dword load, 16 distinct addresses (4-way dup over g)
    const float bv = bias[(size_t)site * COUTD + o];

    float acc[BATCH] = {0.f, 0.f, 0.f, 0.f};

    // w <= 125: float4 row loads read columns w-1..w+2 <= 127, always in-bounds.
    const bool interior = (h >= 1) & (h <= HWD - 2) & (w >= 1) & (w <= HWD - 3);

    if (interior) {
        #pragma unroll
        for (int cc = 0; cc < 4; ++cc) {
            #pragma unroll
            for (int b = 0; b < BATCH; ++b) {
                const float* xb = x + (((size_t)(b * CIND + c0 + cc) * HWD + (h - 1)) * HWD) + (w - 1);
                // three window rows as dword-aligned float4 (4th elem unused)
                f4 r0 = *(const f4u*)(xb);
                f4 r1 = *(const f4u*)(xb + HWD);
                f4 r2 = *(const f4u*)(xb + 2 * HWD);
                const float* wr = wf + cc * 9;
                acc[b] = fmaf(r0.x, wr[0], acc[b]);
                acc[b] = fmaf(r0.y, wr[1], acc[b]);
                acc[b] = fmaf(r0.z, wr[2], acc[b]);
                acc[b] = fmaf(r1.x, wr[3], acc[b]);
                acc[b] = fmaf(r1.y, wr[4], acc[b]);
                acc[b] = fmaf(r1.z, wr[5], acc[b]);
                acc[b] = fmaf(r2.x, wr[6], acc[b]);
                acc[b] = fmaf(r2.y, wr[7], acc[b]);
                acc[b] = fmaf(r2.z, wr[8], acc[b]);
            }
        }
    } else {
        #pragma unroll
        for (int cc = 0; cc < 4; ++cc) {
            #pragma unroll
            for (int b = 0; b < BATCH; ++b) {
                const float* xb = x + ((size_t)(b * CIND + c0 + cc)) * (HWD * HWD);
                #pragma unroll
                for (int kh = 0; kh < 3; ++kh) {
                    const int hy = h + kh - 1;
                    #pragma unroll
                    for (int kw = 0; kw < 3; ++kw) {
                        const int wx = w + kw - 1;
                        const bool ok = (hy >= 0) & (hy < HWD) & (wx >= 0) & (wx < HWD);
                        const float xv = ok ? xb[hy * HWD + wx] : 0.f;
                        acc[b] = fmaf(xv, wf[cc * 9 + kh * 3 + kw], acc[b]);
                    }
                }
            }
        }
    }

    // ---- butterfly reduce over the 4 c-groups: all lanes end with full sums ----
    float r[BATCH];
    #pragma unroll
    for (int b = 0; b < BATCH; ++b) {
        float v = acc[b];
        v += __shfl_xor(v, 32);
        v += __shfl_xor(v, 16);
        r[b] = v;
    }

    // lane (g,o) stores batch b = g: one store instruction, all 64 lanes active
    const float vout = (g == 0) ? r[0] : (g == 1) ? r[1] : (g == 2) ? r[2] : r[3];
    out[((size_t)(g * COUTD + o)) * (HWD * HWD) + h * HWD + w] = vout + bv;
}

extern "C" void kernel_launch(void* const* d_in, const int* in_sizes, int n_in,
                              void* d_out, int out_size, void* d_ws, size_t ws_size,
                              hipStream_t stream) {
    const float* x    = (const float*)d_in[0];
    const float* wts  = (const float*)d_in[1];
    const float* bias = (const float*)d_in[2];
    float* out = (float*)d_out;

    // 16384 sites, 4 waves (= 4 sites) per 256-thread block.
    const int blocks = (HWD * HWD) / 4;
    xonv2d_kernel<<<blocks, 256, 0, stream>>>(x, wts, bias, out);
}

// Round 6
// 225.223 us; speedup vs baseline: 1.7271x; 1.2089x over previous
//
#include <hip/hip_runtime.h>

// Xonv2D: location-dependent 3x3 conv.
//   x:       (B=4, CIN=16, H=128, W=128)  fp32
//   weights: (H, W, COUT=16, CIN=16, 3, 3) fp32   -- 151 MB, the traffic driver
//   bias:    (H, W, COUT) fp32
//   out:     (B, COUT, H, W) fp32
//
// V5 (resubmit -- round 5 was a container infra failure, kernel never ran):
// coalesced weight fetch + wave-local LDS transpose (NO barrier).
//  v4's weight loads were per-lane float4 at 144B inter-lane stride: every
//  global_load_dwordx4 touched 64 distinct cache lines (16B used each),
//  throttling the stream to ~1.1 TB/s on per-CU miss concurrency. Now the
//  wave loads its site's 9216B block CONTIGUOUSLY (lane l takes float4
//  j*64+l: 16 lines/instr, the m13 6.3TB/s pattern), ds_write_b128's them
//  into the wave's private 9KB LDS slice, and ds_read_b128's back the
//  per-lane (o,g) 36-float fragment. Producer wave == consumer wave, so no
//  __syncthreads (v2's mistake) -- only compiler vmcnt/lgkmcnt waits; waves
//  stay fully independent. 36KB/block -> 4 blocks/CU (16 waves/CU).
//
// Kept from v4: x window rows as dword-aligned float4 (w<=125 fast path so
// the 4th element never leaves the buffer), wave-uniform border path, XCD
// banding (blockIdx%8 -> 2048-site band), butterfly reduce + single store.

#define HWD  128
#define CIND 16
#define COUTD 16
#define BATCH 4

typedef float f4  __attribute__((ext_vector_type(4)));
typedef float f4u __attribute__((ext_vector_type(4), aligned(4)));

__global__ __launch_bounds__(256) void xonv2d_kernel(
    const float* __restrict__ x,
    const float* __restrict__ wts,
    const float* __restrict__ bias,
    float* __restrict__ out)
{
    __shared__ f4 wsm[4][576];   // 4 waves x 9216 B

    const int lane = threadIdx.x & 63;
    const int wave = threadIdx.x >> 6;

    // XCD banding: XCD k = blockIdx%8 handles sites [k*2048, (k+1)*2048).
    const int xcd = blockIdx.x & 7;
    const int idx = blockIdx.x >> 3;
    const int site = xcd * 2048 + idx * 4 + wave;   // 0 .. 16383
    const int h = site >> 7;
    const int w = site & 127;

    const int o = lane & 15;    // output channel
    const int g = lane >> 4;    // channel group: c in [4g, 4g+4)
    const int c0 = g * 4;

    // ---- coalesced weight fetch: site's 576 float4s, lane l takes j*64+l ----
    const f4* gw = (const f4*)wts + (size_t)site * 576;
    f4 st[9];
    #pragma unroll
    for (int j = 0; j < 9; ++j)
        st[j] = __builtin_nontemporal_load(gw + j * 64 + lane);

    // bias: one dword load (issues while weight loads are in flight)
    const float bv = bias[(size_t)site * COUTD + o];

    // ---- wave-local LDS transpose: write coalesced order, read (o,g) frags ----
    #pragma unroll
    for (int j = 0; j < 9; ++j)
        wsm[wave][j * 64 + lane] = st[j];            // ds_write_b128

    f4 wv[9];
    {
        const f4* lp = &wsm[wave][o * 36 + g * 9];
        #pragma unroll
        for (int j = 0; j < 9; ++j) wv[j] = lp[j];   // ds_read_b128
    }
    const float* wf = (const float*)wv;

    float acc[BATCH] = {0.f, 0.f, 0.f, 0.f};

    // w <= 125: float4 row loads read columns w-1..w+2 <= 127, always in-bounds.
    const bool interior = (h >= 1) & (h <= HWD - 2) & (w >= 1) & (w <= HWD - 3);

    if (interior) {
        #pragma unroll
        for (int cc = 0; cc < 4; ++cc) {
            #pragma unroll
            for (int b = 0; b < BATCH; ++b) {
                const float* xb = x + (((size_t)(b * CIND + c0 + cc) * HWD + (h - 1)) * HWD) + (w - 1);
                f4 r0 = *(const f4u*)(xb);
                f4 r1 = *(const f4u*)(xb + HWD);
                f4 r2 = *(const f4u*)(xb + 2 * HWD);
                const float* wr = wf + cc * 9;
                acc[b] = fmaf(r0.x, wr[0], acc[b]);
                acc[b] = fmaf(r0.y, wr[1], acc[b]);
                acc[b] = fmaf(r0.z, wr[2], acc[b]);
                acc[b] = fmaf(r1.x, wr[3], acc[b]);
                acc[b] = fmaf(r1.y, wr[4], acc[b]);
                acc[b] = fmaf(r1.z, wr[5], acc[b]);
                acc[b] = fmaf(r2.x, wr[6], acc[b]);
                acc[b] = fmaf(r2.y, wr[7], acc[b]);
                acc[b] = fmaf(r2.z, wr[8], acc[b]);
            }
        }
    } else {
        #pragma unroll
        for (int cc = 0; cc < 4; ++cc) {
            #pragma unroll
            for (int b = 0; b < BATCH; ++b) {
                const float* xb = x + ((size_t)(b * CIND + c0 + cc)) * (HWD * HWD);
                #pragma unroll
                for (int kh = 0; kh < 3; ++kh) {
                    const int hy = h + kh - 1;
                    #pragma unroll
                    for (int kw = 0; kw < 3; ++kw) {
                        const int wx = w + kw - 1;
                        const bool ok = (hy >= 0) & (hy < HWD) & (wx >= 0) & (wx < HWD);
                        const float xv = ok ? xb[hy * HWD + wx] : 0.f;
                        acc[b] = fmaf(xv, wf[cc * 9 + kh * 3 + kw], acc[b]);
                    }
                }
            }
        }
    }

    // ---- butterfly reduce over the 4 c-groups: all lanes end with full sums ----
    float r[BATCH];
    #pragma unroll
    for (int b = 0; b < BATCH; ++b) {
        float v = acc[b];
        v += __shfl_xor(v, 32);
        v += __shfl_xor(v, 16);
        r[b] = v;
    }

    // lane (g,o) stores batch b = g: one store instruction, all 64 lanes active
    const float vout = (g == 0) ? r[0] : (g == 1) ? r[1] : (g == 2) ? r[2] : r[3];
    out[((size_t)(g * COUTD + o)) * (HWD * HWD) + h * HWD + w] = vout + bv;
}

extern "C" void kernel_launch(void* const* d_in, const int* in_sizes, int n_in,
                              void* d_out, int out_size, void* d_ws, size_t ws_size,
                              hipStream_t stream) {
    const float* x    = (const float*)d_in[0];
    const float* wts  = (const float*)d_in[1];
    const float* bias = (const float*)d_in[2];
    float* out = (float*)d_out;

    // 16384 sites, 4 waves (= 4 sites) per 256-thread block.
    const int blocks = (HWD * HWD) / 4;
    xonv2d_kernel<<<blocks, 256, 0, stream>>>(x, wts, bias, out);
}